// Round 1
// baseline (95.364 us; speedup 1.0000x reference)
//
#include <hip/hip_runtime.h>

// DepthToSpace 3D, block=2, channels_last.
// in:  (4, 32, 64, 64, 128) fp32
// out: (4, 64, 128, 128, 16) fp32
// out[n, 2z+dz, 2y+dy, 2x+dx, c] = in[n, z, y, x, (dz*4+dy*2+dx)*16 + c]

__global__ __launch_bounds__(256) void d2s_kernel(const float4* __restrict__ in4,
                                                  float4* __restrict__ out4,
                                                  int n4) {
    int idx = blockIdx.x * blockDim.x + threadIdx.x;
    if (idx >= n4) return;

    // Output float4 index decomposition.
    // out float layout: (n, Z(64), Y(128), X(128), c(16)) -> float4: c4 in [0,4)
    unsigned int c4 = idx & 3u;
    unsigned int t  = (unsigned int)idx >> 2;
    unsigned int X  = t & 127u;  t >>= 7;
    unsigned int Y  = t & 127u;  t >>= 7;
    unsigned int Z  = t & 63u;
    unsigned int n  = t >> 6;

    unsigned int x = X >> 1, dx = X & 1u;
    unsigned int y = Y >> 1, dy = Y & 1u;
    unsigned int z = Z >> 1, dz = Z & 1u;
    unsigned int i = dz * 4u + dy * 2u + dx;

    // input float4 index: (((n*32+z)*64+y)*64+x)*32 + i*4 + c4
    unsigned int in_idx = ((((n * 32u + z) * 64u + y) * 64u + x) << 5) + (i << 2) + c4;

    out4[idx] = in4[in_idx];
}

extern "C" void kernel_launch(void* const* d_in, const int* in_sizes, int n_in,
                              void* d_out, int out_size, void* d_ws, size_t ws_size,
                              hipStream_t stream) {
    const float4* in4 = (const float4*)d_in[0];
    float4* out4 = (float4*)d_out;
    int n4 = out_size / 4;  // 16,777,216
    int block = 256;
    int grid = (n4 + block - 1) / block;
    d2s_kernel<<<grid, block, 0, stream>>>(in4, out4, n4);
}